// Round 7
// baseline (102.655 us; speedup 1.0000x reference)
//
#include <hip/hip_runtime.h>
#include <math.h>

#define B_SZ 32
#define N_NODES 4096
#define C_DIM 64
#define M_EDGES 64
#define DEG 256
#define E_INC 16384
#define NEG_SLOPE 0.2f
#define MARGIN 4.2f

__device__ __forceinline__ float wsum64(float v) {
#pragma unroll
  for (int off = 32; off > 0; off >>= 1) v += __shfl_xor(v, off, 64);
  return v;
}

__device__ __forceinline__ float4 redq16_32(float4 a) {
#pragma unroll
  for (int off = 16; off < 64; off <<= 1) {
    a.x += __shfl_xor(a.x, off, 64);
    a.y += __shfl_xor(a.y, off, 64);
    a.z += __shfl_xor(a.z, off, 64);
    a.w += __shfl_xor(a.w, off, 64);
  }
  return a;
}

union U16K {
  float wl[4096];
  int cnt[4096];
};

// P1: bid<2048 edge-sum gather (fused s1 writes, fused s2/nrm2/essum);
//     bid>=2048 per-edge incidence counts (coalesced rows).
__global__ __launch_bounds__(256) void k_p1(
    const float* __restrict__ x, const float* __restrict__ w,
    const float* __restrict__ att, const int* __restrict__ node_ids,
    float* __restrict__ s1_t, float* __restrict__ es_t,
    float* __restrict__ s2, float* __restrict__ nrm2,
    float* __restrict__ essum, int* __restrict__ cntv) {
  __shared__ U16K u;
  __shared__ float part[4][64];
  __shared__ float wattl[64];
  __shared__ float sx[4][64];
  __shared__ float sxc[64];
  const int bid = blockIdx.x;
  const int t = threadIdx.x;
  if (bid < 2048) {
    const int b = 4 * (bid & 7) + ((bid >> 3) & 3);
    const int m = bid >> 5;
    const int lane = t & 63, wv = t >> 6;
    const int qc = lane & 15, rsub = lane >> 4;
    // W -> LDS
    float4* wl4 = (float4*)u.wl;
    const float4* w4 = (const float4*)w;
#pragma unroll
    for (int i = 0; i < 4; ++i) wl4[t + 256 * i] = w4[t + 256 * i];
    // watt = W @ att[0:64]
    {
      const int kk = t & 63, q = t >> 6;
      float p = 0.f;
#pragma unroll
      for (int c = 0; c < 16; ++c)
        p = fmaf(w[kk * 64 + q * 16 + c], att[q * 16 + c], p);
      part[q][kk] = p;
    }
    __syncthreads();
    if (t < 64)
      wattl[t] = part[0][t] + part[1][t] + part[2][t] + part[3][t];
    __syncthreads();
    const float4 wq = ((const float4*)wattl)[qc];
    const float4* xb4 = (const float4*)(x + (size_t)b * (N_NODES * C_DIM));
    const int rbase = m * DEG + wv * 64 + rsub;
    float4 acc = {0.f, 0.f, 0.f, 0.f};
#pragma unroll
    for (int i = 0; i < 16; ++i) {
      const int node = node_ids[rbase + i * 4];
      const float4 xv = xb4[node * 16 + qc];
      acc.x += xv.x;
      acc.y += xv.y;
      acc.z += xv.z;
      acc.w += xv.w;
      // fused s1: dot(x_row, W@att0) via 16-lane reduce (dup writes identical)
      float sv = xv.x * wq.x + xv.y * wq.y + xv.z * wq.z + xv.w * wq.w;
      sv += __shfl_xor(sv, 1, 64);
      sv += __shfl_xor(sv, 2, 64);
      sv += __shfl_xor(sv, 4, 64);
      sv += __shfl_xor(sv, 8, 64);
      if (qc == 0) s1_t[node * 32 + b] = sv;
    }
    acc = redq16_32(acc);
    if (rsub == 0) ((float4*)sx[wv])[qc] = acc;
    __syncthreads();
    if (t < 64) {
      sxc[t] = sx[0][t] + sx[1][t] + sx[2][t] + sx[3][t];
      float es = 0.f;
#pragma unroll 8
      for (int j = 0; j < 64; ++j) es = fmaf(sxc[j], u.wl[j * 64 + t], es);
      es_t[(m * 64 + t) * 32 + b] = es;
      const float sr = wsum64(es * att[64 + t]);
      const float nr = wsum64(es * es);
      const float er = wsum64(es);
      if (t == 0) {
        s2[m * 32 + b] = sr;
        nrm2[m * 32 + b] = nr;
        essum[m * 32 + b] = er;
      }
    }
  } else {
    const int m = bid - 2048;
#pragma unroll
    for (int i = 0; i < 16; ++i) u.cnt[t + 256 * i] = 0;
    __syncthreads();
    atomicAdd(&u.cnt[node_ids[m * DEG + t]], 1);
    __syncthreads();
#pragma unroll
    for (int i = 0; i < 16; ++i)
      cntv[m * N_NODES + t + 256 * i] = u.cnt[t + 256 * i];
  }
}

// P2: bid<504 upper-triangle pairwise loss (2016 pairs, diag==0, 2x factor);
//     bid>=504 branch-free per-(n,b) online softmax + packed node->edge lists.
__global__ __launch_bounds__(256) void k_p2(
    const float* __restrict__ es_t, const float* __restrict__ nrm2,
    const int* __restrict__ cntv, const float* __restrict__ s1_t,
    const float* __restrict__ s2, float* __restrict__ lossbuf2,
    float2* __restrict__ pnb, int* __restrict__ pdat,
    int* __restrict__ plen) {
  const int bid = blockIdx.x;
  if (bid < 504) {
    const int wv = threadIdx.x >> 6;
    const int p = bid * 4 + wv;
    int k = 0, off = 0;
    while (off + (63 - k) <= p) {
      off += 63 - k;
      ++k;
    }
    const int m = k + 1 + (p - off);
    const int lane = threadIdx.x & 63;
    const int b = lane & 31, ch = lane >> 5;
    float inner = 0.f;
#pragma unroll 8
    for (int cc = 0; cc < 32; ++cc) {
      const int c = cc + 32 * ch;
      inner = fmaf(es_t[(k * 64 + c) * 32 + b], es_t[(m * 64 + c) * 32 + b],
                   inner);
    }
    inner += __shfl_xor(inner, 32, 64);
    const float nk2 = nrm2[k * 32 + b];
    const float nm2 = nrm2[m * 32 + b];
    const float d2 = fmaxf(nk2 + nm2 - 2.f * inner, 0.f);
    const float dist = sqrtf(d2);
    const float cosv = inner / sqrtf(nk2 * nm2);
    float li = cosv * dist + (1.f - cosv) * fmaxf(MARGIN - dist, 0.f);
#pragma unroll
    for (int o = 16; o > 0; o >>= 1) li += __shfl_xor(li, o, 64);
    if (lane == 0) lossbuf2[p] = 2.f * fabsf(li * (1.f / 32.f));
  } else {
    const int idx = (bid - 504) * 256 + threadIdx.x;
    const int n = idx >> 5, b = idx & 31;
    const float s1v = s1_t[n * 32 + b];
    const bool leader = (b == 0);
    float mx = -1e30f, S = 0.f;
    int j = 0, Dsum = 0;
#pragma unroll 4
    for (int m = 0; m < 64; ++m) {
      const int cm = cntv[m * N_NODES + n];
      float sc = s1v + s2[m * 32 + b];
      sc = sc > 0.f ? sc : NEG_SLOPE * sc;
      const float scv = (cm > 0) ? sc : -1e30f;
      const float nm = fmaxf(mx, scv);
      S = S * __expf(mx - nm) + (float)cm * __expf(scv - nm);
      mx = nm;
      if (leader) {
        if (cm > 0) {
          pdat[n * 64 + j] = m | (cm << 8);
          ++j;
        }
        Dsum += cm;
      }
    }
    if (leader) plen[n] = j | (Dsum << 7);
    float2 pv;
    pv.x = mx;
    pv.y = (S > 0.f) ? 1.f / S : 0.f;
    pnb[n * 32 + b] = pv;
  }
}

// P3: bid<2048 alpha-weighted gather + @W epilogue; bid==2048 final scalar.
__global__ __launch_bounds__(256) void k_p3(
    const float* __restrict__ x, const int* __restrict__ node_ids,
    const float* __restrict__ w, const float* __restrict__ s1_t,
    const float* __restrict__ s2, const float2* __restrict__ pnb,
    const float* __restrict__ essum, const float* __restrict__ lossbuf2,
    float* __restrict__ out_e_t, float* __restrict__ outs) {
  __shared__ U16K u;
  __shared__ float sx[4][64];
  __shared__ float sxc[64];
  const int bid = blockIdx.x;
  const int t = threadIdx.x;
  if (bid < 2048) {
    const int b = 4 * (bid & 7) + ((bid >> 3) & 3);
    const int m = bid >> 5;
    const int lane = t & 63, wv = t >> 6;
    const int qc = lane & 15, rsub = lane >> 4;
    float4* wl4 = (float4*)u.wl;
    const float4* w4 = (const float4*)w;
#pragma unroll
    for (int i = 0; i < 4; ++i) wl4[t + 256 * i] = w4[t + 256 * i];
    const float4* xb4 = (const float4*)(x + (size_t)b * (N_NODES * C_DIM));
    const float s2mb = s2[m * 32 + b];
    const int rbase = m * DEG + wv * 64 + rsub;
    float4 acc = {0.f, 0.f, 0.f, 0.f};
#pragma unroll
    for (int i = 0; i < 16; ++i) {
      const int node = node_ids[rbase + i * 4];
      const float s1v = s1_t[node * 32 + b];
      const float2 pv = pnb[node * 32 + b];
      float sc = s1v + s2mb;
      sc = sc > 0.f ? sc : NEG_SLOPE * sc;
      const float a = __expf(sc - pv.x) * pv.y;
      const float4 xv = xb4[node * 16 + qc];
      acc.x = fmaf(a, xv.x, acc.x);
      acc.y = fmaf(a, xv.y, acc.y);
      acc.z = fmaf(a, xv.z, acc.z);
      acc.w = fmaf(a, xv.w, acc.w);
    }
    acc = redq16_32(acc);
    if (rsub == 0) ((float4*)sx[wv])[qc] = acc;
    __syncthreads();
    if (t < 64) {
      sxc[t] = sx[0][t] + sx[1][t] + sx[2][t] + sx[3][t];
      float oc = 0.f;
#pragma unroll 8
      for (int j = 0; j < 64; ++j) oc = fmaf(sxc[j], u.wl[j * 64 + t], oc);
      out_e_t[(m * 64 + t) * 32 + b] = oc * (1.0f / 256.0f);
    }
  } else {
    __shared__ float smf[256];
    float s = 0.f;
    for (int i = t; i < M_EDGES * B_SZ; i += 256) s += essum[i];
    smf[t] = s;
    __syncthreads();
    for (int o = 128; o > 0; o >>= 1) {
      if (t < o) smf[t] += smf[t + o];
      __syncthreads();
    }
    const float S = smf[0];
    __syncthreads();
    float l = 0.f;
    for (int i = t; i < 2016; i += 256) l += lossbuf2[i];
    smf[t] = l;
    __syncthreads();
    for (int o = 128; o > 0; o >>= 1) {
      if (t < o) smf[t] += smf[t + o];
      __syncthreads();
    }
    if (t == 0) {
      const float mean = S * (-255.0f) / 33554432.0f;  // sum(x_i-x_j)=-255*S
      outs[0] = fabsf(mean) + smf[0] * (1.0f / 4225.0f);
    }
  }
}

// P4: per node, packed edge list (coalesced header); alpha in LDS;
// out[b,n,c] = D[n] * sum_m cnt*alpha(n,m,b)*out_e_t[m,c,b]
__global__ __launch_bounds__(256) void k_p4(
    const int* __restrict__ plen, const int* __restrict__ pdat,
    const float* __restrict__ s1_t, const float* __restrict__ s2,
    const float2* __restrict__ pnb, const float* __restrict__ out_e_t,
    float* __restrict__ out) {
  __shared__ int lme[64];
  __shared__ float lcnt[64];
  __shared__ float al[64][32];
  const int n = blockIdx.x;
  const int t = threadIdx.x;
  const int pl = plen[n];
  const int len = pl & 127;
  const float Dn = (float)(pl >> 7);
  const int c = t & 63, bq = t >> 6;
  const size_t nb = (size_t)n * 64 + c;
  const size_t st = (size_t)N_NODES * 64;
  if (len == 0) {
#pragma unroll
    for (int j = 0; j < 8; ++j) out[(bq * 8 + j) * st + nb] = 0.f;
    return;
  }
  if (t < len) {
    const int pe = pdat[n * 64 + t];
    lme[t] = pe & 63;
    lcnt[t] = (float)(pe >> 8);
  }
  __syncthreads();
  {
    const int b = t & 31, lq = t >> 5;
    const float s1v = s1_t[n * 32 + b];
    const float2 pv = pnb[n * 32 + b];
    for (int base = 0; base < len; base += 8) {
      const int li = base + lq;
      if (li < len) {
        const int m = lme[li];
        float sc = s1v + s2[m * 32 + b];
        sc = sc > 0.f ? sc : NEG_SLOPE * sc;
        al[li][b] = lcnt[li] * __expf(sc - pv.x) * pv.y;
      }
    }
  }
  __syncthreads();
  float4 a0 = {0.f, 0.f, 0.f, 0.f}, a1 = {0.f, 0.f, 0.f, 0.f};
  for (int li = 0; li < len; ++li) {
    const int m = lme[li];
    const float4 v0 = *(const float4*)&out_e_t[(m * 64 + c) * 32 + bq * 8];
    const float4 v1 = *(const float4*)&out_e_t[(m * 64 + c) * 32 + bq * 8 + 4];
    const float* alr = al[li];
    a0.x = fmaf(alr[bq * 8 + 0], v0.x, a0.x);
    a0.y = fmaf(alr[bq * 8 + 1], v0.y, a0.y);
    a0.z = fmaf(alr[bq * 8 + 2], v0.z, a0.z);
    a0.w = fmaf(alr[bq * 8 + 3], v0.w, a0.w);
    a1.x = fmaf(alr[bq * 8 + 4], v1.x, a1.x);
    a1.y = fmaf(alr[bq * 8 + 5], v1.y, a1.y);
    a1.z = fmaf(alr[bq * 8 + 6], v1.z, a1.z);
    a1.w = fmaf(alr[bq * 8 + 7], v1.w, a1.w);
  }
  out[(bq * 8 + 0) * st + nb] = Dn * a0.x;
  out[(bq * 8 + 1) * st + nb] = Dn * a0.y;
  out[(bq * 8 + 2) * st + nb] = Dn * a0.z;
  out[(bq * 8 + 3) * st + nb] = Dn * a0.w;
  out[(bq * 8 + 4) * st + nb] = Dn * a1.x;
  out[(bq * 8 + 5) * st + nb] = Dn * a1.y;
  out[(bq * 8 + 6) * st + nb] = Dn * a1.z;
  out[(bq * 8 + 7) * st + nb] = Dn * a1.w;
}

extern "C" void kernel_launch(void* const* d_in, const int* in_sizes, int n_in,
                              void* d_out, int out_size, void* d_ws,
                              size_t ws_size, hipStream_t stream) {
  (void)in_sizes; (void)n_in; (void)out_size; (void)ws_size;
  const float* x = (const float*)d_in[0];
  const float* weight = (const float*)d_in[1];
  const float* att = (const float*)d_in[2];
  const int* node_ids = (const int*)d_in[3];
  float* out = (float*)d_out;

  char* wsb = (char*)d_ws;
  float* es_t = (float*)(wsb);                     // 512KB [m,c,b]
  float* out_e_t = (float*)(wsb + (512 << 10));    // 512KB [m,c,b]
  float* s1_t = (float*)(wsb + (1024 << 10));      // 512KB [n,b]
  int* cntv = (int*)(wsb + (1536 << 10));          // 1MB   [m,n]
  float2* pnb = (float2*)(wsb + (2560 << 10));     // 1MB   [n,b] {mx,invS}
  int* pdat = (int*)(wsb + (3584 << 10));          // 1MB   [n,64] packed m|cnt
  float* s2 = (float*)(wsb + (4608 << 10));        // 8KB
  float* nrm2 = (float*)(wsb + (4616 << 10));      // 8KB
  float* essum = (float*)(wsb + (4624 << 10));     // 8KB
  float* lossbuf2 = (float*)(wsb + (4632 << 10));  // 8KB (2016 floats)
  int* plen = (int*)(wsb + (4640 << 10));          // 16KB [n] len|Dsum<<7

  k_p1<<<2112, 256, 0, stream>>>(x, weight, att, node_ids, s1_t, es_t, s2,
                                 nrm2, essum, cntv);
  k_p2<<<1016, 256, 0, stream>>>(es_t, nrm2, cntv, s1_t, s2, lossbuf2, pnb,
                                 pdat, plen);
  k_p3<<<2049, 256, 0, stream>>>(x, node_ids, weight, s1_t, s2, pnb, essum,
                                 lossbuf2, out_e_t,
                                 out + (size_t)B_SZ * N_NODES * C_DIM);
  k_p4<<<4096, 256, 0, stream>>>(plen, pdat, s1_t, s2, pnb, out_e_t, out);
}

// Round 8
// 90.332 us; speedup vs baseline: 1.1364x; 1.1364x over previous
//
#include <hip/hip_runtime.h>
#include <math.h>

#define B_SZ 32
#define N_NODES 4096
#define C_DIM 64
#define M_EDGES 64
#define DEG 256
#define E_INC 16384
#define NEG_SLOPE 0.2f
#define MARGIN 4.2f

__device__ __forceinline__ float wsum64(float v) {
#pragma unroll
  for (int off = 32; off > 0; off >>= 1) v += __shfl_xor(v, off, 64);
  return v;
}

__device__ __forceinline__ float4 redq16_32(float4 a) {
#pragma unroll
  for (int off = 16; off < 64; off <<= 1) {
    a.x += __shfl_xor(a.x, off, 64);
    a.y += __shfl_xor(a.y, off, 64);
    a.z += __shfl_xor(a.z, off, 64);
    a.w += __shfl_xor(a.w, off, 64);
  }
  return a;
}

union U16K {
  float wl[4096];
  int cnt[4096];
};

// P1: bid<2048 edge-sum gather (batched loads, shfl node broadcast);
//     bid<2112 per-edge incidence counts; else s1 streaming pass.
__global__ __launch_bounds__(256) void k_p1(
    const float* __restrict__ x, const float* __restrict__ w,
    const float* __restrict__ att, const int* __restrict__ node_ids,
    float* __restrict__ s1_t, float* __restrict__ es_t,
    float* __restrict__ s2, float* __restrict__ nrm2,
    float* __restrict__ essum, int* __restrict__ cntv) {
  __shared__ U16K u;
  __shared__ float sx[4][64];
  __shared__ float part2[4][64];
  const int bid = blockIdx.x;
  const int t = threadIdx.x;
  if (bid < 2048) {
    const int b = 4 * (bid & 7) + ((bid >> 3) & 3);
    const int m = bid >> 5;
    const int lane = t & 63, wv = t >> 6;
    const int qc = lane & 15, rsub = lane >> 4;
    float4* wl4 = (float4*)u.wl;
    const float4* w4 = (const float4*)w;
#pragma unroll
    for (int i = 0; i < 4; ++i) wl4[t + 256 * i] = w4[t + 256 * i];
    const float4* xb4 = (const float4*)(x + (size_t)b * (N_NODES * C_DIM));
    const int myinc = node_ids[m * DEG + wv * 64 + lane];  // 1 coalesced load
    float4 acc = {0.f, 0.f, 0.f, 0.f};
#pragma unroll
    for (int h = 0; h < 2; ++h) {
      int nds[8];
#pragma unroll
      for (int j = 0; j < 8; ++j)
        nds[j] = __shfl(myinc, (h * 8 + j) * 4 + rsub, 64);
      float4 xv[8];
#pragma unroll
      for (int j = 0; j < 8; ++j) xv[j] = xb4[nds[j] * 16 + qc];
#pragma unroll
      for (int j = 0; j < 8; ++j) {
        acc.x += xv[j].x;
        acc.y += xv[j].y;
        acc.z += xv[j].z;
        acc.w += xv[j].w;
      }
    }
    acc = redq16_32(acc);
    if (rsub == 0) ((float4*)sx[wv])[qc] = acc;
    __syncthreads();
    // parallel @W epilogue: wave wv covers j in [16wv,16wv+16)
    {
      const int c = t & 63;
      float ep = 0.f;
#pragma unroll
      for (int jj = 0; jj < 16; ++jj) {
        const int j = wv * 16 + jj;
        const float sxcj = sx[0][j] + sx[1][j] + sx[2][j] + sx[3][j];
        ep = fmaf(sxcj, u.wl[j * 64 + c], ep);
      }
      part2[wv][c] = ep;
    }
    __syncthreads();
    if (t < 64) {
      const float es = part2[0][t] + part2[1][t] + part2[2][t] + part2[3][t];
      es_t[(m * 64 + t) * 32 + b] = es;
      const float sr = wsum64(es * att[64 + t]);
      const float nr = wsum64(es * es);
      const float er = wsum64(es);
      if (t == 0) {
        s2[m * 32 + b] = sr;
        nrm2[m * 32 + b] = nr;
        essum[m * 32 + b] = er;
      }
    }
  } else if (bid < 2112) {
    const int m = bid - 2048;
#pragma unroll
    for (int i = 0; i < 16; ++i) u.cnt[t + 256 * i] = 0;
    __syncthreads();
    atomicAdd(&u.cnt[node_ids[m * DEG + t]], 1);
    __syncthreads();
#pragma unroll
    for (int i = 0; i < 16; ++i)
      cntv[m * N_NODES + t + 256 * i] = u.cnt[t + 256 * i];
  } else {
    // s1 role: s1_t[n*32+b] = dot(x[b,n,:], W@att0)
    __shared__ float part[4][64];
    __shared__ float wattl[64];
    const int sb = bid - 2112;
    const int kk = t & 63, q = t >> 6;
    float p = 0.f;
#pragma unroll
    for (int c = 0; c < 16; ++c)
      p = fmaf(w[kk * 64 + q * 16 + c], att[q * 16 + c], p);
    part[q][kk] = p;
    __syncthreads();
    if (t < 64)
      wattl[t] = part[0][t] + part[1][t] + part[2][t] + part[3][t];
    __syncthreads();
    const int lane = t & 63, wv = t >> 6;
    const int kq = lane & 15, rsub = lane >> 4;
    const float4 wq = ((const float4*)wattl)[kq];
    const int r0 = sb * 256 + wv * 64;
#pragma unroll 4
    for (int it = 0; it < 16; ++it) {
      const int row = r0 + it * 4 + rsub;
      const float4 xv = ((const float4*)x)[row * 16 + kq];
      float vv = xv.x * wq.x + xv.y * wq.y + xv.z * wq.z + xv.w * wq.w;
      vv += __shfl_xor(vv, 1, 64);
      vv += __shfl_xor(vv, 2, 64);
      vv += __shfl_xor(vv, 4, 64);
      vv += __shfl_xor(vv, 8, 64);
      if (kq == 0) {
        const int n = row & (N_NODES - 1);
        const int b = row >> 12;
        s1_t[n * 32 + b] = vv;
      }
    }
  }
}

// P2: bid<504 upper-triangle pairwise loss; else branch-free per-(n,b)
// online softmax + packed node->edge lists.
__global__ __launch_bounds__(256) void k_p2(
    const float* __restrict__ es_t, const float* __restrict__ nrm2,
    const int* __restrict__ cntv, const float* __restrict__ s1_t,
    const float* __restrict__ s2, float* __restrict__ lossbuf2,
    float2* __restrict__ pnb, int* __restrict__ pdat,
    int* __restrict__ plen) {
  const int bid = blockIdx.x;
  if (bid < 504) {
    const int wv = threadIdx.x >> 6;
    const int p = bid * 4 + wv;
    int k = 0, off = 0;
    while (off + (63 - k) <= p) {
      off += 63 - k;
      ++k;
    }
    const int m = k + 1 + (p - off);
    const int lane = threadIdx.x & 63;
    const int b = lane & 31, ch = lane >> 5;
    float inner = 0.f;
#pragma unroll 8
    for (int cc = 0; cc < 32; ++cc) {
      const int c = cc + 32 * ch;
      inner = fmaf(es_t[(k * 64 + c) * 32 + b], es_t[(m * 64 + c) * 32 + b],
                   inner);
    }
    inner += __shfl_xor(inner, 32, 64);
    const float nk2 = nrm2[k * 32 + b];
    const float nm2 = nrm2[m * 32 + b];
    const float d2 = fmaxf(nk2 + nm2 - 2.f * inner, 0.f);
    const float dist = sqrtf(d2);
    const float cosv = inner / sqrtf(nk2 * nm2);
    float li = cosv * dist + (1.f - cosv) * fmaxf(MARGIN - dist, 0.f);
#pragma unroll
    for (int o = 16; o > 0; o >>= 1) li += __shfl_xor(li, o, 64);
    if (lane == 0) lossbuf2[p] = 2.f * fabsf(li * (1.f / 32.f));
  } else {
    const int idx = (bid - 504) * 256 + threadIdx.x;
    const int n = idx >> 5, b = idx & 31;
    const float s1v = s1_t[n * 32 + b];
    const bool leader = (b == 0);
    float mx = -1e30f, S = 0.f;
    int j = 0, Dsum = 0;
#pragma unroll 4
    for (int m = 0; m < 64; ++m) {
      const int cm = cntv[m * N_NODES + n];
      float sc = s1v + s2[m * 32 + b];
      sc = sc > 0.f ? sc : NEG_SLOPE * sc;
      const float scv = (cm > 0) ? sc : -1e30f;
      const float nm = fmaxf(mx, scv);
      S = S * __expf(mx - nm) + (float)cm * __expf(scv - nm);
      mx = nm;
      if (leader) {
        if (cm > 0) {
          pdat[n * 64 + j] = m | (cm << 8);
          ++j;
        }
        Dsum += cm;
      }
    }
    if (leader) plen[n] = j | (Dsum << 7);
    float2 pv;
    pv.x = mx;
    pv.y = (S > 0.f) ? 1.f / S : 0.f;
    pnb[n * 32 + b] = pv;
  }
}

// P3: bid<2048 alpha-weighted gather (per-lane alpha hoisted, batched loads);
//     bid==2048 final scalar.
__global__ __launch_bounds__(256) void k_p3(
    const float* __restrict__ x, const int* __restrict__ node_ids,
    const float* __restrict__ w, const float* __restrict__ s1_t,
    const float* __restrict__ s2, const float2* __restrict__ pnb,
    const float* __restrict__ essum, const float* __restrict__ lossbuf2,
    float* __restrict__ out_e_t, float* __restrict__ outs) {
  __shared__ U16K u;
  __shared__ float sx[4][64];
  __shared__ float part2[4][64];
  const int bid = blockIdx.x;
  const int t = threadIdx.x;
  if (bid < 2048) {
    const int b = 4 * (bid & 7) + ((bid >> 3) & 3);
    const int m = bid >> 5;
    const int lane = t & 63, wv = t >> 6;
    const int qc = lane & 15, rsub = lane >> 4;
    float4* wl4 = (float4*)u.wl;
    const float4* w4 = (const float4*)w;
#pragma unroll
    for (int i = 0; i < 4; ++i) wl4[t + 256 * i] = w4[t + 256 * i];
    const float4* xb4 = (const float4*)(x + (size_t)b * (N_NODES * C_DIM));
    const float s2mb = s2[m * 32 + b];
    // per-lane: alpha for OWN incidence (one scatter-load pair per lane)
    const int myinc = node_ids[m * DEG + wv * 64 + lane];
    const float s1v = s1_t[myinc * 32 + b];
    const float2 pv = pnb[myinc * 32 + b];
    float scl = s1v + s2mb;
    scl = scl > 0.f ? scl : NEG_SLOPE * scl;
    const float mya = __expf(scl - pv.x) * pv.y;
    float4 acc = {0.f, 0.f, 0.f, 0.f};
#pragma unroll
    for (int h = 0; h < 2; ++h) {
      int nds[8];
      float av[8];
#pragma unroll
      for (int j = 0; j < 8; ++j) {
        const int idx = (h * 8 + j) * 4 + rsub;
        nds[j] = __shfl(myinc, idx, 64);
        av[j] = __shfl(mya, idx, 64);
      }
      float4 xv[8];
#pragma unroll
      for (int j = 0; j < 8; ++j) xv[j] = xb4[nds[j] * 16 + qc];
#pragma unroll
      for (int j = 0; j < 8; ++j) {
        acc.x = fmaf(av[j], xv[j].x, acc.x);
        acc.y = fmaf(av[j], xv[j].y, acc.y);
        acc.z = fmaf(av[j], xv[j].z, acc.z);
        acc.w = fmaf(av[j], xv[j].w, acc.w);
      }
    }
    acc = redq16_32(acc);
    if (rsub == 0) ((float4*)sx[wv])[qc] = acc;
    __syncthreads();
    {
      const int c = t & 63;
      float ep = 0.f;
#pragma unroll
      for (int jj = 0; jj < 16; ++jj) {
        const int j = wv * 16 + jj;
        const float sxcj = sx[0][j] + sx[1][j] + sx[2][j] + sx[3][j];
        ep = fmaf(sxcj, u.wl[j * 64 + c], ep);
      }
      part2[wv][c] = ep;
    }
    __syncthreads();
    if (t < 64) {
      const float oc =
          part2[0][t] + part2[1][t] + part2[2][t] + part2[3][t];
      out_e_t[(m * 64 + t) * 32 + b] = oc * (1.0f / 256.0f);
    }
  } else {
    __shared__ float smf[256];
    float s = 0.f;
    for (int i = t; i < M_EDGES * B_SZ; i += 256) s += essum[i];
    smf[t] = s;
    __syncthreads();
    for (int o = 128; o > 0; o >>= 1) {
      if (t < o) smf[t] += smf[t + o];
      __syncthreads();
    }
    const float S = smf[0];
    __syncthreads();
    float l = 0.f;
    for (int i = t; i < 2016; i += 256) l += lossbuf2[i];
    smf[t] = l;
    __syncthreads();
    for (int o = 128; o > 0; o >>= 1) {
      if (t < o) smf[t] += smf[t + o];
      __syncthreads();
    }
    if (t == 0) {
      const float mean = S * (-255.0f) / 33554432.0f;  // sum(x_i-x_j)=-255*S
      outs[0] = fabsf(mean) + smf[0] * (1.0f / 4225.0f);
    }
  }
}

// P4: per node, packed edge list; alpha in LDS; coalesced header.
__global__ __launch_bounds__(256) void k_p4(
    const int* __restrict__ plen, const int* __restrict__ pdat,
    const float* __restrict__ s1_t, const float* __restrict__ s2,
    const float2* __restrict__ pnb, const float* __restrict__ out_e_t,
    float* __restrict__ out) {
  __shared__ int lme[64];
  __shared__ float lcnt[64];
  __shared__ float al[64][32];
  const int n = blockIdx.x;
  const int t = threadIdx.x;
  const int pl = plen[n];
  const int len = pl & 127;
  const float Dn = (float)(pl >> 7);
  const int c = t & 63, bq = t >> 6;
  const size_t nb = (size_t)n * 64 + c;
  const size_t st = (size_t)N_NODES * 64;
  if (len == 0) {
#pragma unroll
    for (int j = 0; j < 8; ++j) out[(bq * 8 + j) * st + nb] = 0.f;
    return;
  }
  if (t < len) {
    const int pe = pdat[n * 64 + t];
    lme[t] = pe & 63;
    lcnt[t] = (float)(pe >> 8);
  }
  __syncthreads();
  {
    const int b = t & 31, lq = t >> 5;
    const float s1v = s1_t[n * 32 + b];
    const float2 pv = pnb[n * 32 + b];
    for (int base = 0; base < len; base += 8) {
      const int li = base + lq;
      if (li < len) {
        const int m = lme[li];
        float sc = s1v + s2[m * 32 + b];
        sc = sc > 0.f ? sc : NEG_SLOPE * sc;
        al[li][b] = lcnt[li] * __expf(sc - pv.x) * pv.y;
      }
    }
  }
  __syncthreads();
  float4 a0 = {0.f, 0.f, 0.f, 0.f}, a1 = {0.f, 0.f, 0.f, 0.f};
  for (int li = 0; li < len; ++li) {
    const int m = lme[li];
    const float4 v0 = *(const float4*)&out_e_t[(m * 64 + c) * 32 + bq * 8];
    const float4 v1 = *(const float4*)&out_e_t[(m * 64 + c) * 32 + bq * 8 + 4];
    const float* alr = al[li];
    a0.x = fmaf(alr[bq * 8 + 0], v0.x, a0.x);
    a0.y = fmaf(alr[bq * 8 + 1], v0.y, a0.y);
    a0.z = fmaf(alr[bq * 8 + 2], v0.z, a0.z);
    a0.w = fmaf(alr[bq * 8 + 3], v0.w, a0.w);
    a1.x = fmaf(alr[bq * 8 + 4], v1.x, a1.x);
    a1.y = fmaf(alr[bq * 8 + 5], v1.y, a1.y);
    a1.z = fmaf(alr[bq * 8 + 6], v1.z, a1.z);
    a1.w = fmaf(alr[bq * 8 + 7], v1.w, a1.w);
  }
  out[(bq * 8 + 0) * st + nb] = Dn * a0.x;
  out[(bq * 8 + 1) * st + nb] = Dn * a0.y;
  out[(bq * 8 + 2) * st + nb] = Dn * a0.z;
  out[(bq * 8 + 3) * st + nb] = Dn * a0.w;
  out[(bq * 8 + 4) * st + nb] = Dn * a1.x;
  out[(bq * 8 + 5) * st + nb] = Dn * a1.y;
  out[(bq * 8 + 6) * st + nb] = Dn * a1.z;
  out[(bq * 8 + 7) * st + nb] = Dn * a1.w;
}

extern "C" void kernel_launch(void* const* d_in, const int* in_sizes, int n_in,
                              void* d_out, int out_size, void* d_ws,
                              size_t ws_size, hipStream_t stream) {
  (void)in_sizes; (void)n_in; (void)out_size; (void)ws_size;
  const float* x = (const float*)d_in[0];
  const float* weight = (const float*)d_in[1];
  const float* att = (const float*)d_in[2];
  const int* node_ids = (const int*)d_in[3];
  float* out = (float*)d_out;

  char* wsb = (char*)d_ws;
  float* es_t = (float*)(wsb);                     // 512KB [m,c,b]
  float* out_e_t = (float*)(wsb + (512 << 10));    // 512KB [m,c,b]
  float* s1_t = (float*)(wsb + (1024 << 10));      // 512KB [n,b]
  int* cntv = (int*)(wsb + (1536 << 10));          // 1MB   [m,n]
  float2* pnb = (float2*)(wsb + (2560 << 10));     // 1MB   [n,b] {mx,invS}
  int* pdat = (int*)(wsb + (3584 << 10));          // 1MB   [n,64] packed m|cnt
  float* s2 = (float*)(wsb + (4608 << 10));        // 8KB
  float* nrm2 = (float*)(wsb + (4616 << 10));      // 8KB
  float* essum = (float*)(wsb + (4624 << 10));     // 8KB
  float* lossbuf2 = (float*)(wsb + (4632 << 10));  // 8KB (2016 floats)
  int* plen = (int*)(wsb + (4640 << 10));          // 16KB [n] len|Dsum<<7

  k_p1<<<2624, 256, 0, stream>>>(x, weight, att, node_ids, s1_t, es_t, s2,
                                 nrm2, essum, cntv);
  k_p2<<<1016, 256, 0, stream>>>(es_t, nrm2, cntv, s1_t, s2, lossbuf2, pnb,
                                 pdat, plen);
  k_p3<<<2049, 256, 0, stream>>>(x, node_ids, weight, s1_t, s2, pnb, essum,
                                 lossbuf2, out_e_t,
                                 out + (size_t)B_SZ * N_NODES * C_DIM);
  k_p4<<<4096, 256, 0, stream>>>(plen, pdat, s1_t, s2, pnb, out_e_t, out);
}

// Round 9
// 88.319 us; speedup vs baseline: 1.1623x; 1.0228x over previous
//
#include <hip/hip_runtime.h>
#include <hip/hip_fp16.h>
#include <math.h>

#define B_SZ 32
#define N_NODES 4096
#define C_DIM 64
#define M_EDGES 64
#define DEG 256
#define E_INC 16384
#define NEG_SLOPE 0.2f
#define MARGIN 4.2f

__device__ __forceinline__ float wsum64(float v) {
#pragma unroll
  for (int off = 32; off > 0; off >>= 1) v += __shfl_xor(v, off, 64);
  return v;
}

// P0: bid<1024 stream x: s1 (fp32) + fp16 conversion; bid>=1024 per-edge counts.
__global__ __launch_bounds__(256) void k_p0(
    const float* __restrict__ x, const float* __restrict__ w,
    const float* __restrict__ att, const int* __restrict__ node_ids,
    float* __restrict__ s1_t, __half* __restrict__ xh,
    int* __restrict__ cntv) {
  const int bid = blockIdx.x;
  const int t = threadIdx.x;
  if (bid < 1024) {
    __shared__ float part[4][64];
    __shared__ float wattl[64];
    const int kk = t & 63, q = t >> 6;
    float p = 0.f;
#pragma unroll
    for (int c = 0; c < 16; ++c)
      p = fmaf(w[kk * 64 + q * 16 + c], att[q * 16 + c], p);
    part[q][kk] = p;
    __syncthreads();
    if (t < 64)
      wattl[t] = part[0][t] + part[1][t] + part[2][t] + part[3][t];
    __syncthreads();
    const int lane = t & 63, wv = t >> 6;
    const int kq = lane & 15, rsub = lane >> 4;
    const float4 wq = ((const float4*)wattl)[kq];
    const int r0 = bid * 128 + wv * 32;
#pragma unroll 4
    for (int it = 0; it < 8; ++it) {
      const int row = r0 + it * 4 + rsub;
      const float4 xv = ((const float4*)x)[row * 16 + kq];
      float vv = xv.x * wq.x + xv.y * wq.y + xv.z * wq.z + xv.w * wq.w;
      vv += __shfl_xor(vv, 1, 64);
      vv += __shfl_xor(vv, 2, 64);
      vv += __shfl_xor(vv, 4, 64);
      vv += __shfl_xor(vv, 8, 64);
      if (kq == 0) {
        const int n = row & (N_NODES - 1);
        const int b = row >> 12;
        s1_t[n * 32 + b] = vv;
      }
      union {
        __half2 h2[2];
        uint2 u;
      } pk;
      pk.h2[0] = __halves2half2(__float2half(xv.x), __float2half(xv.y));
      pk.h2[1] = __halves2half2(__float2half(xv.z), __float2half(xv.w));
      ((uint2*)xh)[row * 16 + kq] = pk.u;
    }
  } else {
    __shared__ int cnt[N_NODES];
    const int m = bid - 1024;
#pragma unroll
    for (int i = 0; i < 16; ++i) cnt[t + 256 * i] = 0;
    __syncthreads();
    atomicAdd(&cnt[node_ids[m * DEG + t]], 1);
    __syncthreads();
#pragma unroll
    for (int i = 0; i < 16; ++i)
      cntv[m * N_NODES + t + 256 * i] = cnt[t + 256 * i];
  }
}

// P1: edge-sum gather from fp16 x (L2-resident panels), fp32 @W epilogue.
__global__ __launch_bounds__(256) void k_p1(
    const __half* __restrict__ xh, const float* __restrict__ w,
    const float* __restrict__ att, const int* __restrict__ node_ids,
    float* __restrict__ es_t, float* __restrict__ s2,
    float* __restrict__ nrm2, float* __restrict__ essum) {
  __shared__ float wl[4096];
  __shared__ float sx[4][64];
  __shared__ float part2[4][64];
  const int bid = blockIdx.x;
  const int t = threadIdx.x;
  const int b = 4 * (bid & 7) + ((bid >> 3) & 3);
  const int m = bid >> 5;
  const int lane = t & 63, wv = t >> 6;
  const int co = lane & 7, rg = lane >> 3;
  float4* wl4 = (float4*)wl;
  const float4* w4 = (const float4*)w;
#pragma unroll
  for (int i = 0; i < 4; ++i) wl4[t + 256 * i] = w4[t + 256 * i];
  const uint4* xb = (const uint4*)(xh + (size_t)b * (N_NODES * C_DIM));
  const int myinc = node_ids[m * DEG + wv * 64 + lane];
  int nds[8];
#pragma unroll
  for (int j = 0; j < 8; ++j) nds[j] = __shfl(myinc, j * 8 + rg, 64);
  uint4 v[8];
#pragma unroll
  for (int j = 0; j < 8; ++j) v[j] = xb[nds[j] * 8 + co];
  float acc[8] = {0.f, 0.f, 0.f, 0.f, 0.f, 0.f, 0.f, 0.f};
#pragma unroll
  for (int j = 0; j < 8; ++j) {
    const __half2* hp = (const __half2*)&v[j];
#pragma unroll
    for (int q = 0; q < 4; ++q) {
      const float2 f2 = __half22float2(hp[q]);
      acc[2 * q] += f2.x;
      acc[2 * q + 1] += f2.y;
    }
  }
#pragma unroll
  for (int off = 8; off < 64; off <<= 1) {
#pragma unroll
    for (int k = 0; k < 8; ++k) acc[k] += __shfl_xor(acc[k], off, 64);
  }
  if (rg == 0) {
    ((float4*)&sx[wv][co * 8])[0] =
        make_float4(acc[0], acc[1], acc[2], acc[3]);
    ((float4*)&sx[wv][co * 8])[1] =
        make_float4(acc[4], acc[5], acc[6], acc[7]);
  }
  __syncthreads();
  {
    const int c = t & 63;
    float ep = 0.f;
#pragma unroll
    for (int jj = 0; jj < 16; ++jj) {
      const int j = wv * 16 + jj;
      const float sxcj = sx[0][j] + sx[1][j] + sx[2][j] + sx[3][j];
      ep = fmaf(sxcj, wl[j * 64 + c], ep);
    }
    part2[wv][c] = ep;
  }
  __syncthreads();
  if (t < 64) {
    const float es = part2[0][t] + part2[1][t] + part2[2][t] + part2[3][t];
    es_t[(m * 64 + t) * 32 + b] = es;
    const float sr = wsum64(es * att[64 + t]);
    const float nr = wsum64(es * es);
    const float er = wsum64(es);
    if (t == 0) {
      s2[m * 32 + b] = sr;
      nrm2[m * 32 + b] = nr;
      essum[m * 32 + b] = er;
    }
  }
}

// P2: bid<504 upper-triangle pairwise loss; else branch-free per-(n,b)
// online softmax + packed node->edge lists.
__global__ __launch_bounds__(256) void k_p2(
    const float* __restrict__ es_t, const float* __restrict__ nrm2,
    const int* __restrict__ cntv, const float* __restrict__ s1_t,
    const float* __restrict__ s2, float* __restrict__ lossbuf2,
    float2* __restrict__ pnb, int* __restrict__ pdat,
    int* __restrict__ plen) {
  const int bid = blockIdx.x;
  if (bid < 504) {
    const int wv = threadIdx.x >> 6;
    const int p = bid * 4 + wv;
    int k = 0, off = 0;
    while (off + (63 - k) <= p) {
      off += 63 - k;
      ++k;
    }
    const int m = k + 1 + (p - off);
    const int lane = threadIdx.x & 63;
    const int b = lane & 31, ch = lane >> 5;
    float inner = 0.f;
#pragma unroll 8
    for (int cc = 0; cc < 32; ++cc) {
      const int c = cc + 32 * ch;
      inner = fmaf(es_t[(k * 64 + c) * 32 + b], es_t[(m * 64 + c) * 32 + b],
                   inner);
    }
    inner += __shfl_xor(inner, 32, 64);
    const float nk2 = nrm2[k * 32 + b];
    const float nm2 = nrm2[m * 32 + b];
    const float d2 = fmaxf(nk2 + nm2 - 2.f * inner, 0.f);
    const float dist = sqrtf(d2);
    const float cosv = inner / sqrtf(nk2 * nm2);
    float li = cosv * dist + (1.f - cosv) * fmaxf(MARGIN - dist, 0.f);
#pragma unroll
    for (int o = 16; o > 0; o >>= 1) li += __shfl_xor(li, o, 64);
    if (lane == 0) lossbuf2[p] = 2.f * fabsf(li * (1.f / 32.f));
  } else {
    const int idx = (bid - 504) * 256 + threadIdx.x;
    const int n = idx >> 5, b = idx & 31;
    const float s1v = s1_t[n * 32 + b];
    const bool leader = (b == 0);
    float mx = -1e30f, S = 0.f;
    int j = 0, Dsum = 0;
#pragma unroll 4
    for (int m = 0; m < 64; ++m) {
      const int cm = cntv[m * N_NODES + n];
      float sc = s1v + s2[m * 32 + b];
      sc = sc > 0.f ? sc : NEG_SLOPE * sc;
      const float scv = (cm > 0) ? sc : -1e30f;
      const float nm = fmaxf(mx, scv);
      S = S * __expf(mx - nm) + (float)cm * __expf(scv - nm);
      mx = nm;
      if (leader) {
        if (cm > 0) {
          pdat[n * 64 + j] = m | (cm << 8);
          ++j;
        }
        Dsum += cm;
      }
    }
    if (leader) plen[n] = j | (Dsum << 7);
    float2 pv;
    pv.x = mx;
    pv.y = (S > 0.f) ? 1.f / S : 0.f;
    pnb[n * 32 + b] = pv;
  }
}

// P3: bid<2048 alpha-weighted fp16 gather + fp32 @W; bid==2048 final scalar.
__global__ __launch_bounds__(256) void k_p3(
    const __half* __restrict__ xh, const int* __restrict__ node_ids,
    const float* __restrict__ w, const float* __restrict__ s1_t,
    const float* __restrict__ s2, const float2* __restrict__ pnb,
    const float* __restrict__ essum, const float* __restrict__ lossbuf2,
    float* __restrict__ out_e_t, float* __restrict__ outs) {
  __shared__ float wl[4096];
  __shared__ float sx[4][64];
  __shared__ float part2[4][64];
  const int bid = blockIdx.x;
  const int t = threadIdx.x;
  if (bid < 2048) {
    const int b = 4 * (bid & 7) + ((bid >> 3) & 3);
    const int m = bid >> 5;
    const int lane = t & 63, wv = t >> 6;
    const int co = lane & 7, rg = lane >> 3;
    float4* wl4 = (float4*)wl;
    const float4* w4 = (const float4*)w;
#pragma unroll
    for (int i = 0; i < 4; ++i) wl4[t + 256 * i] = w4[t + 256 * i];
    const uint4* xb = (const uint4*)(xh + (size_t)b * (N_NODES * C_DIM));
    const float s2mb = s2[m * 32 + b];
    const int myinc = node_ids[m * DEG + wv * 64 + lane];
    const float s1v = s1_t[myinc * 32 + b];
    const float2 pv = pnb[myinc * 32 + b];
    float scl = s1v + s2mb;
    scl = scl > 0.f ? scl : NEG_SLOPE * scl;
    const float mya = __expf(scl - pv.x) * pv.y;
    int nds[8];
    float av[8];
#pragma unroll
    for (int j = 0; j < 8; ++j) {
      nds[j] = __shfl(myinc, j * 8 + rg, 64);
      av[j] = __shfl(mya, j * 8 + rg, 64);
    }
    uint4 v[8];
#pragma unroll
    for (int j = 0; j < 8; ++j) v[j] = xb[nds[j] * 8 + co];
    float acc[8] = {0.f, 0.f, 0.f, 0.f, 0.f, 0.f, 0.f, 0.f};
#pragma unroll
    for (int j = 0; j < 8; ++j) {
      const __half2* hp = (const __half2*)&v[j];
#pragma unroll
      for (int q = 0; q < 4; ++q) {
        const float2 f2 = __half22float2(hp[q]);
        acc[2 * q] = fmaf(av[j], f2.x, acc[2 * q]);
        acc[2 * q + 1] = fmaf(av[j], f2.y, acc[2 * q + 1]);
      }
    }
#pragma unroll
    for (int off = 8; off < 64; off <<= 1) {
#pragma unroll
      for (int k = 0; k < 8; ++k) acc[k] += __shfl_xor(acc[k], off, 64);
    }
    if (rg == 0) {
      ((float4*)&sx[wv][co * 8])[0] =
          make_float4(acc[0], acc[1], acc[2], acc[3]);
      ((float4*)&sx[wv][co * 8])[1] =
          make_float4(acc[4], acc[5], acc[6], acc[7]);
    }
    __syncthreads();
    {
      const int c = t & 63;
      float ep = 0.f;
#pragma unroll
      for (int jj = 0; jj < 16; ++jj) {
        const int j = wv * 16 + jj;
        const float sxcj = sx[0][j] + sx[1][j] + sx[2][j] + sx[3][j];
        ep = fmaf(sxcj, wl[j * 64 + c], ep);
      }
      part2[wv][c] = ep;
    }
    __syncthreads();
    if (t < 64) {
      const float oc = part2[0][t] + part2[1][t] + part2[2][t] + part2[3][t];
      out_e_t[(m * 64 + t) * 32 + b] = oc * (1.0f / 256.0f);
    }
  } else {
    __shared__ float smf[256];
    float s = 0.f;
    for (int i = t; i < M_EDGES * B_SZ; i += 256) s += essum[i];
    smf[t] = s;
    __syncthreads();
    for (int o = 128; o > 0; o >>= 1) {
      if (t < o) smf[t] += smf[t + o];
      __syncthreads();
    }
    const float S = smf[0];
    __syncthreads();
    float l = 0.f;
    for (int i = t; i < 2016; i += 256) l += lossbuf2[i];
    smf[t] = l;
    __syncthreads();
    for (int o = 128; o > 0; o >>= 1) {
      if (t < o) smf[t] += smf[t + o];
      __syncthreads();
    }
    if (t == 0) {
      const float mean = S * (-255.0f) / 33554432.0f;  // sum(x_i-x_j)=-255*S
      outs[0] = fabsf(mean) + smf[0] * (1.0f / 4225.0f);
    }
  }
}

// P4: per node, packed edge list; alpha in LDS; coalesced header.
__global__ __launch_bounds__(256) void k_p4(
    const int* __restrict__ plen, const int* __restrict__ pdat,
    const float* __restrict__ s1_t, const float* __restrict__ s2,
    const float2* __restrict__ pnb, const float* __restrict__ out_e_t,
    float* __restrict__ out) {
  __shared__ int lme[64];
  __shared__ float lcnt[64];
  __shared__ float al[64][32];
  const int n = blockIdx.x;
  const int t = threadIdx.x;
  const int pl = plen[n];
  const int len = pl & 127;
  const float Dn = (float)(pl >> 7);
  const int c = t & 63, bq = t >> 6;
  const size_t nb = (size_t)n * 64 + c;
  const size_t st = (size_t)N_NODES * 64;
  if (len == 0) {
#pragma unroll
    for (int j = 0; j < 8; ++j) out[(bq * 8 + j) * st + nb] = 0.f;
    return;
  }
  if (t < len) {
    const int pe = pdat[n * 64 + t];
    lme[t] = pe & 63;
    lcnt[t] = (float)(pe >> 8);
  }
  __syncthreads();
  {
    const int b = t & 31, lq = t >> 5;
    const float s1v = s1_t[n * 32 + b];
    const float2 pv = pnb[n * 32 + b];
    for (int base = 0; base < len; base += 8) {
      const int li = base + lq;
      if (li < len) {
        const int m = lme[li];
        float sc = s1v + s2[m * 32 + b];
        sc = sc > 0.f ? sc : NEG_SLOPE * sc;
        al[li][b] = lcnt[li] * __expf(sc - pv.x) * pv.y;
      }
    }
  }
  __syncthreads();
  float4 a0 = {0.f, 0.f, 0.f, 0.f}, a1 = {0.f, 0.f, 0.f, 0.f};
  for (int li = 0; li < len; ++li) {
    const int m = lme[li];
    const float4 v0 = *(const float4*)&out_e_t[(m * 64 + c) * 32 + bq * 8];
    const float4 v1 = *(const float4*)&out_e_t[(m * 64 + c) * 32 + bq * 8 + 4];
    const float* alr = al[li];
    a0.x = fmaf(alr[bq * 8 + 0], v0.x, a0.x);
    a0.y = fmaf(alr[bq * 8 + 1], v0.y, a0.y);
    a0.z = fmaf(alr[bq * 8 + 2], v0.z, a0.z);
    a0.w = fmaf(alr[bq * 8 + 3], v0.w, a0.w);
    a1.x = fmaf(alr[bq * 8 + 4], v1.x, a1.x);
    a1.y = fmaf(alr[bq * 8 + 5], v1.y, a1.y);
    a1.z = fmaf(alr[bq * 8 + 6], v1.z, a1.z);
    a1.w = fmaf(alr[bq * 8 + 7], v1.w, a1.w);
  }
  out[(bq * 8 + 0) * st + nb] = Dn * a0.x;
  out[(bq * 8 + 1) * st + nb] = Dn * a0.y;
  out[(bq * 8 + 2) * st + nb] = Dn * a0.z;
  out[(bq * 8 + 3) * st + nb] = Dn * a0.w;
  out[(bq * 8 + 4) * st + nb] = Dn * a1.x;
  out[(bq * 8 + 5) * st + nb] = Dn * a1.y;
  out[(bq * 8 + 6) * st + nb] = Dn * a1.z;
  out[(bq * 8 + 7) * st + nb] = Dn * a1.w;
}

extern "C" void kernel_launch(void* const* d_in, const int* in_sizes, int n_in,
                              void* d_out, int out_size, void* d_ws,
                              size_t ws_size, hipStream_t stream) {
  (void)in_sizes; (void)n_in; (void)out_size; (void)ws_size;
  const float* x = (const float*)d_in[0];
  const float* weight = (const float*)d_in[1];
  const float* att = (const float*)d_in[2];
  const int* node_ids = (const int*)d_in[3];
  float* out = (float*)d_out;

  char* wsb = (char*)d_ws;
  float* es_t = (float*)(wsb);                     // 512KB [m,c,b]
  float* out_e_t = (float*)(wsb + (512 << 10));    // 512KB [m,c,b]
  float* s1_t = (float*)(wsb + (1024 << 10));      // 512KB [n,b]
  int* cntv = (int*)(wsb + (1536 << 10));          // 1MB   [m,n]
  float2* pnb = (float2*)(wsb + (2560 << 10));     // 1MB   [n,b] {mx,invS}
  int* pdat = (int*)(wsb + (3584 << 10));          // 1MB   [n,64] packed m|cnt
  float* s2 = (float*)(wsb + (4608 << 10));        // 8KB
  float* nrm2 = (float*)(wsb + (4616 << 10));      // 8KB
  float* essum = (float*)(wsb + (4624 << 10));     // 8KB
  float* lossbuf2 = (float*)(wsb + (4632 << 10));  // 8KB (2016 floats)
  int* plen = (int*)(wsb + (4640 << 10));          // 16KB [n] len|Dsum<<7
  __half* xh = (__half*)(wsb + (5120 << 10));      // 16MB [b,n,c] fp16

  k_p0<<<1088, 256, 0, stream>>>(x, weight, att, node_ids, s1_t, xh, cntv);
  k_p1<<<2048, 256, 0, stream>>>(xh, weight, att, node_ids, es_t, s2, nrm2,
                                 essum);
  k_p2<<<1016, 256, 0, stream>>>(es_t, nrm2, cntv, s1_t, s2, lossbuf2, pnb,
                                 pdat, plen);
  k_p3<<<2049, 256, 0, stream>>>(xh, node_ids, weight, s1_t, s2, pnb, essum,
                                 lossbuf2, out_e_t,
                                 out + (size_t)B_SZ * N_NODES * C_DIM);
  k_p4<<<4096, 256, 0, stream>>>(plen, pdat, s1_t, s2, pnb, out_e_t, out);
}

// Round 10
// 84.454 us; speedup vs baseline: 1.2155x; 1.0458x over previous
//
#include <hip/hip_runtime.h>
#include <hip/hip_fp16.h>
#include <math.h>

#define B_SZ 32
#define N_NODES 4096
#define C_DIM 64
#define M_EDGES 64
#define DEG 256
#define E_INC 16384
#define NEG_SLOPE 0.2f
#define MARGIN 4.2f

__device__ __forceinline__ float wsum64(float v) {
#pragma unroll
  for (int off = 32; off > 0; off >>= 1) v += __shfl_xor(v, off, 64);
  return v;
}

// P0: bid<512 stream x: s1 (fp32) + fp16 conversion (256 rows/block);
//     bid>=512 per-edge counts.
__global__ __launch_bounds__(256) void k_p0(
    const float* __restrict__ x, const float* __restrict__ w,
    const float* __restrict__ att, const int* __restrict__ node_ids,
    float* __restrict__ s1_t, __half* __restrict__ xh,
    int* __restrict__ cntv) {
  const int bid = blockIdx.x;
  const int t = threadIdx.x;
  if (bid < 512) {
    __shared__ float part[4][64];
    __shared__ float wattl[64];
    const int kk = t & 63, q = t >> 6;
    float p = 0.f;
#pragma unroll
    for (int c = 0; c < 16; ++c)
      p = fmaf(w[kk * 64 + q * 16 + c], att[q * 16 + c], p);
    part[q][kk] = p;
    __syncthreads();
    if (t < 64)
      wattl[t] = part[0][t] + part[1][t] + part[2][t] + part[3][t];
    __syncthreads();
    const int lane = t & 63, wv = t >> 6;
    const int kq = lane & 15, rsub = lane >> 4;
    const float4 wq = ((const float4*)wattl)[kq];
    const int r0 = bid * 256 + wv * 64;
#pragma unroll 4
    for (int it = 0; it < 16; ++it) {
      const int row = r0 + it * 4 + rsub;
      const float4 xv = ((const float4*)x)[row * 16 + kq];
      float vv = xv.x * wq.x + xv.y * wq.y + xv.z * wq.z + xv.w * wq.w;
      vv += __shfl_xor(vv, 1, 64);
      vv += __shfl_xor(vv, 2, 64);
      vv += __shfl_xor(vv, 4, 64);
      vv += __shfl_xor(vv, 8, 64);
      if (kq == 0) {
        const int n = row & (N_NODES - 1);
        const int b = row >> 12;
        s1_t[n * 32 + b] = vv;
      }
      union {
        __half2 h2[2];
        uint2 u;
      } pk;
      pk.h2[0] = __halves2half2(__float2half(xv.x), __float2half(xv.y));
      pk.h2[1] = __halves2half2(__float2half(xv.z), __float2half(xv.w));
      ((uint2*)xh)[row * 16 + kq] = pk.u;
    }
  } else {
    __shared__ int cnt[N_NODES];
    const int m = bid - 512;
#pragma unroll
    for (int i = 0; i < 16; ++i) cnt[t + 256 * i] = 0;
    __syncthreads();
    atomicAdd(&cnt[node_ids[m * DEG + t]], 1);
    __syncthreads();
#pragma unroll
    for (int i = 0; i < 16; ++i)
      cntv[m * N_NODES + t + 256 * i] = cnt[t + 256 * i];
  }
}

// P1: edge-sums. Block = (m, b-quad). 2048->512 blocks; wave-parallel epilogue.
__global__ __launch_bounds__(256) void k_p1(
    const __half* __restrict__ xh, const float* __restrict__ w,
    const float* __restrict__ att, const int* __restrict__ node_ids,
    float* __restrict__ es_t, float* __restrict__ s2,
    float* __restrict__ nrm2, float* __restrict__ essum) {
  __shared__ float wl[4096];
  __shared__ float sx[4][4][64];  // [wave][bi][c]
  __shared__ float est[4][64];    // [bi][c]
  const int bid = blockIdx.x;
  const int bg = bid & 7;  // XCD
  const int m = bid >> 3;
  const int b0 = bg * 4;
  const int t = threadIdx.x;
  const int lane = t & 63, wv = t >> 6;
  const int co = lane & 7, rg = lane >> 3;
  float4* wl4 = (float4*)wl;
  const float4* w4 = (const float4*)w;
#pragma unroll
  for (int i = 0; i < 4; ++i) wl4[t + 256 * i] = w4[t + 256 * i];
  const int myinc = node_ids[m * DEG + wv * 64 + lane];
  int nds[8];
#pragma unroll
  for (int j = 0; j < 8; ++j) nds[j] = __shfl(myinc, j * 8 + rg, 64);
#pragma unroll
  for (int bi = 0; bi < 4; ++bi) {
    const uint4* xb =
        (const uint4*)(xh + (size_t)(b0 + bi) * (N_NODES * C_DIM));
    uint4 v[8];
#pragma unroll
    for (int j = 0; j < 8; ++j) v[j] = xb[nds[j] * 8 + co];
    float acc[8] = {0.f, 0.f, 0.f, 0.f, 0.f, 0.f, 0.f, 0.f};
#pragma unroll
    for (int j = 0; j < 8; ++j) {
      const __half2* hp = (const __half2*)&v[j];
#pragma unroll
      for (int q = 0; q < 4; ++q) {
        const float2 f2 = __half22float2(hp[q]);
        acc[2 * q] += f2.x;
        acc[2 * q + 1] += f2.y;
      }
    }
#pragma unroll
    for (int off = 8; off < 64; off <<= 1) {
#pragma unroll
      for (int k = 0; k < 8; ++k) acc[k] += __shfl_xor(acc[k], off, 64);
    }
    if (rg == 0) {
      ((float4*)&sx[wv][bi][co * 8])[0] =
          make_float4(acc[0], acc[1], acc[2], acc[3]);
      ((float4*)&sx[wv][bi][co * 8])[1] =
          make_float4(acc[4], acc[5], acc[6], acc[7]);
    }
  }
  __syncthreads();
  // wave wv finalizes b = b0+wv
  {
    const int c = lane;
    float es = 0.f;
#pragma unroll 8
    for (int j = 0; j < 64; ++j) {
      const float sxcj =
          sx[0][wv][j] + sx[1][wv][j] + sx[2][wv][j] + sx[3][wv][j];
      es = fmaf(sxcj, wl[j * 64 + c], es);
    }
    est[wv][c] = es;
    const float sr = wsum64(es * att[64 + c]);
    const float nr = wsum64(es * es);
    const float er = wsum64(es);
    if (c == 0) {
      s2[m * 32 + b0 + wv] = sr;
      nrm2[m * 32 + b0 + wv] = nr;
      essum[m * 32 + b0 + wv] = er;
    }
  }
  __syncthreads();
  if (t < 64) {
    const float4 o = make_float4(est[0][t], est[1][t], est[2][t], est[3][t]);
    *(float4*)&es_t[(m * 64 + t) * 32 + b0] = o;
  }
}

// P2: bid<504 upper-triangle pairwise loss; else branch-free per-(n,b)
// online softmax + packed node->edge lists.
__global__ __launch_bounds__(256) void k_p2(
    const float* __restrict__ es_t, const float* __restrict__ nrm2,
    const int* __restrict__ cntv, const float* __restrict__ s1_t,
    const float* __restrict__ s2, float* __restrict__ lossbuf2,
    float2* __restrict__ pnb, int* __restrict__ pdat,
    int* __restrict__ plen) {
  const int bid = blockIdx.x;
  if (bid < 504) {
    const int wv = threadIdx.x >> 6;
    const int p = bid * 4 + wv;
    int k = 0, off = 0;
    while (off + (63 - k) <= p) {
      off += 63 - k;
      ++k;
    }
    const int m = k + 1 + (p - off);
    const int lane = threadIdx.x & 63;
    const int b = lane & 31, ch = lane >> 5;
    float inner = 0.f;
#pragma unroll 8
    for (int cc = 0; cc < 32; ++cc) {
      const int c = cc + 32 * ch;
      inner = fmaf(es_t[(k * 64 + c) * 32 + b], es_t[(m * 64 + c) * 32 + b],
                   inner);
    }
    inner += __shfl_xor(inner, 32, 64);
    const float nk2 = nrm2[k * 32 + b];
    const float nm2 = nrm2[m * 32 + b];
    const float d2 = fmaxf(nk2 + nm2 - 2.f * inner, 0.f);
    const float dist = sqrtf(d2);
    const float cosv = inner / sqrtf(nk2 * nm2);
    float li = cosv * dist + (1.f - cosv) * fmaxf(MARGIN - dist, 0.f);
#pragma unroll
    for (int o = 16; o > 0; o >>= 1) li += __shfl_xor(li, o, 64);
    if (lane == 0) lossbuf2[p] = 2.f * fabsf(li * (1.f / 32.f));
  } else {
    const int idx = (bid - 504) * 256 + threadIdx.x;
    const int n = idx >> 5, b = idx & 31;
    const float s1v = s1_t[n * 32 + b];
    const bool leader = (b == 0);
    float mx = -1e30f, S = 0.f;
    int j = 0, Dsum = 0;
#pragma unroll 4
    for (int m = 0; m < 64; ++m) {
      const int cm = cntv[m * N_NODES + n];
      float sc = s1v + s2[m * 32 + b];
      sc = sc > 0.f ? sc : NEG_SLOPE * sc;
      const float scv = (cm > 0) ? sc : -1e30f;
      const float nm = fmaxf(mx, scv);
      S = S * __expf(mx - nm) + (float)cm * __expf(scv - nm);
      mx = nm;
      if (leader) {
        if (cm > 0) {
          pdat[n * 64 + j] = m | (cm << 8);
          ++j;
        }
        Dsum += cm;
      }
    }
    if (leader) plen[n] = j | (Dsum << 7);
    float2 pv;
    pv.x = mx;
    pv.y = (S > 0.f) ? 1.f / S : 0.f;
    pnb[n * 32 + b] = pv;
  }
}

// P3: bid<512 alpha-weighted gather, block = (m, b-quad); bid==512 final scalar.
__global__ __launch_bounds__(256) void k_p3(
    const __half* __restrict__ xh, const int* __restrict__ node_ids,
    const float* __restrict__ w, const float* __restrict__ s1_t,
    const float* __restrict__ s2, const float2* __restrict__ pnb,
    const float* __restrict__ essum, const float* __restrict__ lossbuf2,
    float* __restrict__ out_e_t, float* __restrict__ outs) {
  __shared__ float wl[4096];
  __shared__ float sx[4][4][64];
  __shared__ float est[4][64];
  const int bid = blockIdx.x;
  const int t = threadIdx.x;
  if (bid < 512) {
    const int bg = bid & 7;
    const int m = bid >> 3;
    const int b0 = bg * 4;
    const int lane = t & 63, wv = t >> 6;
    const int co = lane & 7, rg = lane >> 3;
    float4* wl4 = (float4*)wl;
    const float4* w4 = (const float4*)w;
#pragma unroll
    for (int i = 0; i < 4; ++i) wl4[t + 256 * i] = w4[t + 256 * i];
    const int myinc = node_ids[m * DEG + wv * 64 + lane];
    // per-lane alpha for the 4 consecutive b's (vector loads)
    const float4 s14 = *(const float4*)&s1_t[myinc * 32 + b0];
    const float* pp = (const float*)&pnb[myinc * 32 + b0];
    const float4 pA = *(const float4*)pp;       // {mx0,inv0,mx1,inv1}
    const float4 pB = *(const float4*)(pp + 4); // {mx2,inv2,mx3,inv3}
    float mya[4];
    {
      const float s1a[4] = {s14.x, s14.y, s14.z, s14.w};
      const float mxa[4] = {pA.x, pA.z, pB.x, pB.z};
      const float iva[4] = {pA.y, pA.w, pB.y, pB.w};
#pragma unroll
      for (int bi = 0; bi < 4; ++bi) {
        float sc = s1a[bi] + s2[m * 32 + b0 + bi];
        sc = sc > 0.f ? sc : NEG_SLOPE * sc;
        mya[bi] = __expf(sc - mxa[bi]) * iva[bi];
      }
    }
    int nds[8];
#pragma unroll
    for (int j = 0; j < 8; ++j) nds[j] = __shfl(myinc, j * 8 + rg, 64);
#pragma unroll
    for (int bi = 0; bi < 4; ++bi) {
      const uint4* xb =
          (const uint4*)(xh + (size_t)(b0 + bi) * (N_NODES * C_DIM));
      float av[8];
#pragma unroll
      for (int j = 0; j < 8; ++j) av[j] = __shfl(mya[bi], j * 8 + rg, 64);
      uint4 v[8];
#pragma unroll
      for (int j = 0; j < 8; ++j) v[j] = xb[nds[j] * 8 + co];
      float acc[8] = {0.f, 0.f, 0.f, 0.f, 0.f, 0.f, 0.f, 0.f};
#pragma unroll
      for (int j = 0; j < 8; ++j) {
        const __half2* hp = (const __half2*)&v[j];
#pragma unroll
        for (int q = 0; q < 4; ++q) {
          const float2 f2 = __half22float2(hp[q]);
          acc[2 * q] = fmaf(av[j], f2.x, acc[2 * q]);
          acc[2 * q + 1] = fmaf(av[j], f2.y, acc[2 * q + 1]);
        }
      }
#pragma unroll
      for (int off = 8; off < 64; off <<= 1) {
#pragma unroll
        for (int k = 0; k < 8; ++k) acc[k] += __shfl_xor(acc[k], off, 64);
      }
      if (rg == 0) {
        ((float4*)&sx[wv][bi][co * 8])[0] =
            make_float4(acc[0], acc[1], acc[2], acc[3]);
        ((float4*)&sx[wv][bi][co * 8])[1] =
            make_float4(acc[4], acc[5], acc[6], acc[7]);
      }
    }
    __syncthreads();
    {
      const int c = lane;
      float oc = 0.f;
#pragma unroll 8
      for (int j = 0; j < 64; ++j) {
        const float sxcj =
            sx[0][wv][j] + sx[1][wv][j] + sx[2][wv][j] + sx[3][wv][j];
        oc = fmaf(sxcj, wl[j * 64 + c], oc);
      }
      est[wv][c] = oc * (1.0f / 256.0f);
    }
    __syncthreads();
    if (t < 64) {
      const float4 o =
          make_float4(est[0][t], est[1][t], est[2][t], est[3][t]);
      *(float4*)&out_e_t[(m * 64 + t) * 32 + b0] = o;
    }
  } else {
    __shared__ float smf[256];
    float s = 0.f;
    for (int i = t; i < M_EDGES * B_SZ; i += 256) s += essum[i];
    smf[t] = s;
    __syncthreads();
    for (int o = 128; o > 0; o >>= 1) {
      if (t < o) smf[t] += smf[t + o];
      __syncthreads();
    }
    const float S = smf[0];
    __syncthreads();
    float l = 0.f;
    for (int i = t; i < 2016; i += 256) l += lossbuf2[i];
    smf[t] = l;
    __syncthreads();
    for (int o = 128; o > 0; o >>= 1) {
      if (t < o) smf[t] += smf[t + o];
      __syncthreads();
    }
    if (t == 0) {
      const float mean = S * (-255.0f) / 33554432.0f;  // sum(x_i-x_j)=-255*S
      outs[0] = fabsf(mean) + smf[0] * (1.0f / 4225.0f);
    }
  }
}

// P4: per node, packed edge list; alpha in LDS; coalesced header.
__global__ __launch_bounds__(256) void k_p4(
    const int* __restrict__ plen, const int* __restrict__ pdat,
    const float* __restrict__ s1_t, const float* __restrict__ s2,
    const float2* __restrict__ pnb, const float* __restrict__ out_e_t,
    float* __restrict__ out) {
  __shared__ int lme[64];
  __shared__ float lcnt[64];
  __shared__ float al[64][32];
  const int n = blockIdx.x;
  const int t = threadIdx.x;
  const int pl = plen[n];
  const int len = pl & 127;
  const float Dn = (float)(pl >> 7);
  const int c = t & 63, bq = t >> 6;
  const size_t nb = (size_t)n * 64 + c;
  const size_t st = (size_t)N_NODES * 64;
  if (len == 0) {
#pragma unroll
    for (int j = 0; j < 8; ++j) out[(bq * 8 + j) * st + nb] = 0.f;
    return;
  }
  if (t < len) {
    const int pe = pdat[n * 64 + t];
    lme[t] = pe & 63;
    lcnt[t] = (float)(pe >> 8);
  }
  __syncthreads();
  {
    const int b = t & 31, lq = t >> 5;
    const float s1v = s1_t[n * 32 + b];
    const float2 pv = pnb[n * 32 + b];
    for (int base = 0; base < len; base += 8) {
      const int li = base + lq;
      if (li < len) {
        const int m = lme[li];
        float sc = s1v + s2[m * 32 + b];
        sc = sc > 0.f ? sc : NEG_SLOPE * sc;
        al[li][b] = lcnt[li] * __expf(sc - pv.x) * pv.y;
      }
    }
  }
  __syncthreads();
  float4 a0 = {0.f, 0.f, 0.f, 0.f}, a1 = {0.f, 0.f, 0.f, 0.f};
  for (int li = 0; li < len; ++li) {
    const int m = lme[li];
    const float4 v0 = *(const float4*)&out_e_t[(m * 64 + c) * 32 + bq * 8];
    const float4 v1 = *(const float4*)&out_e_t[(m * 64 + c) * 32 + bq * 8 + 4];
    const float* alr = al[li];
    a0.x = fmaf(alr[bq * 8 + 0], v0.x, a0.x);
    a0.y = fmaf(alr[bq * 8 + 1], v0.y, a0.y);
    a0.z = fmaf(alr[bq * 8 + 2], v0.z, a0.z);
    a0.w = fmaf(alr[bq * 8 + 3], v0.w, a0.w);
    a1.x = fmaf(alr[bq * 8 + 4], v1.x, a1.x);
    a1.y = fmaf(alr[bq * 8 + 5], v1.y, a1.y);
    a1.z = fmaf(alr[bq * 8 + 6], v1.z, a1.z);
    a1.w = fmaf(alr[bq * 8 + 7], v1.w, a1.w);
  }
  out[(bq * 8 + 0) * st + nb] = Dn * a0.x;
  out[(bq * 8 + 1) * st + nb] = Dn * a0.y;
  out[(bq * 8 + 2) * st + nb] = Dn * a0.z;
  out[(bq * 8 + 3) * st + nb] = Dn * a0.w;
  out[(bq * 8 + 4) * st + nb] = Dn * a1.x;
  out[(bq * 8 + 5) * st + nb] = Dn * a1.y;
  out[(bq * 8 + 6) * st + nb] = Dn * a1.z;
  out[(bq * 8 + 7) * st + nb] = Dn * a1.w;
}

extern "C" void kernel_launch(void* const* d_in, const int* in_sizes, int n_in,
                              void* d_out, int out_size, void* d_ws,
                              size_t ws_size, hipStream_t stream) {
  (void)in_sizes; (void)n_in; (void)out_size; (void)ws_size;
  const float* x = (const float*)d_in[0];
  const float* weight = (const float*)d_in[1];
  const float* att = (const float*)d_in[2];
  const int* node_ids = (const int*)d_in[3];
  float* out = (float*)d_out;

  char* wsb = (char*)d_ws;
  float* es_t = (float*)(wsb);                     // 512KB [m,c,b]
  float* out_e_t = (float*)(wsb + (512 << 10));    // 512KB [m,c,b]
  float* s1_t = (float*)(wsb + (1024 << 10));      // 512KB [n,b]
  int* cntv = (int*)(wsb + (1536 << 10));          // 1MB   [m,n]
  float2* pnb = (float2*)(wsb + (2560 << 10));     // 1MB   [n,b] {mx,invS}
  int* pdat = (int*)(wsb + (3584 << 10));          // 1MB   [n,64] packed m|cnt
  float* s2 = (float*)(wsb + (4608 << 10));        // 8KB
  float* nrm2 = (float*)(wsb + (4616 << 10));      // 8KB
  float* essum = (float*)(wsb + (4624 << 10));     // 8KB
  float* lossbuf2 = (float*)(wsb + (4632 << 10));  // 8KB (2016 floats)
  int* plen = (int*)(wsb + (4640 << 10));          // 16KB [n] len|Dsum<<7
  __half* xh = (__half*)(wsb + (5120 << 10));      // 16MB [b,n,c] fp16

  k_p0<<<576, 256, 0, stream>>>(x, weight, att, node_ids, s1_t, xh, cntv);
  k_p1<<<512, 256, 0, stream>>>(xh, weight, att, node_ids, es_t, s2, nrm2,
                                essum);
  k_p2<<<1016, 256, 0, stream>>>(es_t, nrm2, cntv, s1_t, s2, lossbuf2, pnb,
                                 pdat, plen);
  k_p3<<<513, 256, 0, stream>>>(xh, node_ids, weight, s1_t, s2, pnb, essum,
                                lossbuf2, out_e_t,
                                out + (size_t)B_SZ * N_NODES * C_DIM);
  k_p4<<<4096, 256, 0, stream>>>(plen, pdat, s1_t, s2, pnb, out_e_t, out);
}

// Round 11
// 81.094 us; speedup vs baseline: 1.2659x; 1.0414x over previous
//
#include <hip/hip_runtime.h>
#include <math.h>

#define B_SZ 32
#define N_NODES 4096
#define C_DIM 64
#define M_EDGES 64
#define DEG 256
#define E_INC 16384
#define NEG_SLOPE 0.2f
#define MARGIN 4.2f

__device__ __forceinline__ float wsum64(float v) {
#pragma unroll
  for (int off = 32; off > 0; off >>= 1) v += __shfl_xor(v, off, 64);
  return v;
}

__device__ __forceinline__ float4 redq16_32(float4 a) {
#pragma unroll
  for (int off = 16; off < 64; off <<= 1) {
    a.x += __shfl_xor(a.x, off, 64);
    a.y += __shfl_xor(a.y, off, 64);
    a.z += __shfl_xor(a.z, off, 64);
    a.w += __shfl_xor(a.w, off, 64);
  }
  return a;
}

union U16K {
  float wl[4096];
  int cnt[4096];
};

// Phase A: bid<512 s1 streaming pass; bid<576 per-edge counts;
//          bid>=576 es gather (fp32, b-quad, wave-parallel epilogue).
__global__ __launch_bounds__(256) void k_pA(
    const float* __restrict__ x, const float* __restrict__ w,
    const float* __restrict__ att, const int* __restrict__ node_ids,
    float* __restrict__ s1_t, float* __restrict__ es_t,
    float* __restrict__ s2, float* __restrict__ nrm2,
    float* __restrict__ essum, int* __restrict__ cntv) {
  __shared__ U16K u;
  __shared__ float sx[4][4][64];
  __shared__ float est[4][64];
  const int bid = blockIdx.x;
  const int t = threadIdx.x;
  const int lane = t & 63, wv = t >> 6;
  if (bid < 512) {
    // ---- s1 stream: s1_t[n*32+b] = dot(x[b,n,:], W@att0), 256 rows/block
    __shared__ float part[4][64];
    __shared__ float wattl[64];
    const int kk = t & 63, q = t >> 6;
    float p = 0.f;
#pragma unroll
    for (int c = 0; c < 16; ++c)
      p = fmaf(w[kk * 64 + q * 16 + c], att[q * 16 + c], p);
    part[q][kk] = p;
    __syncthreads();
    if (t < 64)
      wattl[t] = part[0][t] + part[1][t] + part[2][t] + part[3][t];
    __syncthreads();
    const int kq = lane & 15, rsub = lane >> 4;
    const float4 wq = ((const float4*)wattl)[kq];
    const int r0 = bid * 256 + wv * 64;
#pragma unroll 4
    for (int it = 0; it < 16; ++it) {
      const int row = r0 + it * 4 + rsub;
      const float4 xv = ((const float4*)x)[row * 16 + kq];
      float vv = xv.x * wq.x + xv.y * wq.y + xv.z * wq.z + xv.w * wq.w;
      vv += __shfl_xor(vv, 1, 64);
      vv += __shfl_xor(vv, 2, 64);
      vv += __shfl_xor(vv, 4, 64);
      vv += __shfl_xor(vv, 8, 64);
      if (kq == 0) {
        const int n = row & (N_NODES - 1);
        const int b = row >> 12;
        s1_t[n * 32 + b] = vv;
      }
    }
  } else if (bid < 576) {
    // ---- per-edge incidence counts (coalesced rows)
    const int m = bid - 512;
#pragma unroll
    for (int i = 0; i < 16; ++i) u.cnt[t + 256 * i] = 0;
    __syncthreads();
    atomicAdd(&u.cnt[node_ids[m * DEG + t]], 1);
    __syncthreads();
#pragma unroll
    for (int i = 0; i < 16; ++i)
      cntv[m * N_NODES + t + 256 * i] = u.cnt[t + 256 * i];
  } else {
    // ---- es gather: block = (m, b-quad)
    const int eb = bid - 576;
    const int b0 = (eb & 7) * 4;
    const int m = eb >> 3;
    const int qc = lane & 15, rg = lane >> 4;
    float4* wl4 = (float4*)u.wl;
    const float4* w4 = (const float4*)w;
#pragma unroll
    for (int i = 0; i < 4; ++i) wl4[t + 256 * i] = w4[t + 256 * i];
    const int myinc = node_ids[m * DEG + wv * 64 + lane];
    int nds[16];
#pragma unroll
    for (int i = 0; i < 16; ++i) nds[i] = __shfl(myinc, i * 4 + rg, 64);
#pragma unroll
    for (int bi = 0; bi < 4; ++bi) {
      const float4* xb4 =
          (const float4*)(x + (size_t)(b0 + bi) * (N_NODES * C_DIM));
      float4 acc = {0.f, 0.f, 0.f, 0.f};
#pragma unroll
      for (int h = 0; h < 2; ++h) {
        float4 v[8];
#pragma unroll
        for (int j = 0; j < 8; ++j) v[j] = xb4[nds[h * 8 + j] * 16 + qc];
#pragma unroll
        for (int j = 0; j < 8; ++j) {
          acc.x += v[j].x;
          acc.y += v[j].y;
          acc.z += v[j].z;
          acc.w += v[j].w;
        }
      }
      acc = redq16_32(acc);
      if (rg == 0) ((float4*)&sx[wv][bi][0])[qc] = acc;
    }
    __syncthreads();
    {
      const int c = lane;
      float es = 0.f;
#pragma unroll 8
      for (int j = 0; j < 64; ++j) {
        const float sxcj =
            sx[0][wv][j] + sx[1][wv][j] + sx[2][wv][j] + sx[3][wv][j];
        es = fmaf(sxcj, u.wl[j * 64 + c], es);
      }
      est[wv][c] = es;
      const float sr = wsum64(es * att[64 + c]);
      const float nr = wsum64(es * es);
      const float er = wsum64(es);
      if (c == 0) {
        s2[m * 32 + b0 + wv] = sr;
        nrm2[m * 32 + b0 + wv] = nr;
        essum[m * 32 + b0 + wv] = er;
      }
    }
    __syncthreads();
    if (t < 64) {
      const float4 o = make_float4(est[0][t], est[1][t], est[2][t], est[3][t]);
      *(float4*)&es_t[(m * 64 + t) * 32 + b0] = o;
    }
  }
}

// Phase B: bid<504 upper-triangle pairwise loss; else branch-free per-(n,b)
// online softmax + packed node->edge lists.
__global__ __launch_bounds__(256) void k_pB(
    const float* __restrict__ es_t, const float* __restrict__ nrm2,
    const int* __restrict__ cntv, const float* __restrict__ s1_t,
    const float* __restrict__ s2, float* __restrict__ lossbuf2,
    float2* __restrict__ pnb, int* __restrict__ pdat,
    int* __restrict__ plen) {
  const int bid = blockIdx.x;
  if (bid < 504) {
    const int wv = threadIdx.x >> 6;
    const int p = bid * 4 + wv;
    int k = 0, off = 0;
    while (off + (63 - k) <= p) {
      off += 63 - k;
      ++k;
    }
    const int m = k + 1 + (p - off);
    const int lane = threadIdx.x & 63;
    const int b = lane & 31, ch = lane >> 5;
    float inner = 0.f;
#pragma unroll 8
    for (int cc = 0; cc < 32; ++cc) {
      const int c = cc + 32 * ch;
      inner = fmaf(es_t[(k * 64 + c) * 32 + b], es_t[(m * 64 + c) * 32 + b],
                   inner);
    }
    inner += __shfl_xor(inner, 32, 64);
    const float nk2 = nrm2[k * 32 + b];
    const float nm2 = nrm2[m * 32 + b];
    const float d2 = fmaxf(nk2 + nm2 - 2.f * inner, 0.f);
    const float dist = sqrtf(d2);
    const float cosv = inner / sqrtf(nk2 * nm2);
    float li = cosv * dist + (1.f - cosv) * fmaxf(MARGIN - dist, 0.f);
#pragma unroll
    for (int o = 16; o > 0; o >>= 1) li += __shfl_xor(li, o, 64);
    if (lane == 0) lossbuf2[p] = 2.f * fabsf(li * (1.f / 32.f));
  } else {
    const int idx = (bid - 504) * 256 + threadIdx.x;
    const int n = idx >> 5, b = idx & 31;
    const float s1v = s1_t[n * 32 + b];
    const bool leader = (b == 0);
    float mx = -1e30f, S = 0.f;
    int j = 0, Dsum = 0;
#pragma unroll 4
    for (int m = 0; m < 64; ++m) {
      const int cm = cntv[m * N_NODES + n];
      float sc = s1v + s2[m * 32 + b];
      sc = sc > 0.f ? sc : NEG_SLOPE * sc;
      const float scv = (cm > 0) ? sc : -1e30f;
      const float nm = fmaxf(mx, scv);
      S = S * __expf(mx - nm) + (float)cm * __expf(scv - nm);
      mx = nm;
      if (leader) {
        if (cm > 0) {
          pdat[n * 64 + j] = m | (cm << 8);
          ++j;
        }
        Dsum += cm;
      }
    }
    if (leader) plen[n] = j | (Dsum << 7);
    float2 pv;
    pv.x = mx;
    pv.y = (S > 0.f) ? 1.f / S : 0.f;
    pnb[n * 32 + b] = pv;
  }
}

// Phase C: bid<512 alpha-weighted gather (fp32, b-quad); bid==512 final scalar.
__global__ __launch_bounds__(256) void k_pC(
    const float* __restrict__ x, const int* __restrict__ node_ids,
    const float* __restrict__ w, const float* __restrict__ s1_t,
    const float* __restrict__ s2, const float2* __restrict__ pnb,
    const float* __restrict__ essum, const float* __restrict__ lossbuf2,
    float* __restrict__ out_e_t, float* __restrict__ outs) {
  __shared__ float wl[4096];
  __shared__ float sx[4][4][64];
  __shared__ float est[4][64];
  const int bid = blockIdx.x;
  const int t = threadIdx.x;
  if (bid < 512) {
    const int b0 = (bid & 7) * 4;
    const int m = bid >> 3;
    const int lane = t & 63, wv = t >> 6;
    const int qc = lane & 15, rg = lane >> 4;
    float4* wl4 = (float4*)wl;
    const float4* w4 = (const float4*)w;
#pragma unroll
    for (int i = 0; i < 4; ++i) wl4[t + 256 * i] = w4[t + 256 * i];
    const int myinc = node_ids[m * DEG + wv * 64 + lane];
    const float4 s14 = *(const float4*)&s1_t[myinc * 32 + b0];
    const float* pp = (const float*)&pnb[myinc * 32 + b0];
    const float4 pA = *(const float4*)pp;
    const float4 pB = *(const float4*)(pp + 4);
    float mya[4];
    {
      const float s1a[4] = {s14.x, s14.y, s14.z, s14.w};
      const float mxa[4] = {pA.x, pA.z, pB.x, pB.z};
      const float iva[4] = {pA.y, pA.w, pB.y, pB.w};
#pragma unroll
      for (int bi = 0; bi < 4; ++bi) {
        float sc = s1a[bi] + s2[m * 32 + b0 + bi];
        sc = sc > 0.f ? sc : NEG_SLOPE * sc;
        mya[bi] = __expf(sc - mxa[bi]) * iva[bi];
      }
    }
    int nds[16];
#pragma unroll
    for (int i = 0; i < 16; ++i) nds[i] = __shfl(myinc, i * 4 + rg, 64);
#pragma unroll
    for (int bi = 0; bi < 4; ++bi) {
      const float4* xb4 =
          (const float4*)(x + (size_t)(b0 + bi) * (N_NODES * C_DIM));
      float4 acc = {0.f, 0.f, 0.f, 0.f};
#pragma unroll
      for (int h = 0; h < 2; ++h) {
        float4 v[8];
        float av[8];
#pragma unroll
        for (int j = 0; j < 8; ++j) {
          av[j] = __shfl(mya[bi], (h * 8 + j) * 4 + rg, 64);
          v[j] = xb4[nds[h * 8 + j] * 16 + qc];
        }
#pragma unroll
        for (int j = 0; j < 8; ++j) {
          acc.x = fmaf(av[j], v[j].x, acc.x);
          acc.y = fmaf(av[j], v[j].y, acc.y);
          acc.z = fmaf(av[j], v[j].z, acc.z);
          acc.w = fmaf(av[j], v[j].w, acc.w);
        }
      }
      acc = redq16_32(acc);
      if (rg == 0) ((float4*)&sx[wv][bi][0])[qc] = acc;
    }
    __syncthreads();
    {
      const int c = t & 63;
      const int wv2 = t >> 6;
      float oc = 0.f;
#pragma unroll 8
      for (int j = 0; j < 64; ++j) {
        const float sxcj =
            sx[0][wv2][j] + sx[1][wv2][j] + sx[2][wv2][j] + sx[3][wv2][j];
        oc = fmaf(sxcj, wl[j * 64 + c], oc);
      }
      est[wv2][c] = oc * (1.0f / 256.0f);
    }
    __syncthreads();
    if (t < 64) {
      const float4 o = make_float4(est[0][t], est[1][t], est[2][t], est[3][t]);
      *(float4*)&out_e_t[(m * 64 + t) * 32 + b0] = o;
    }
  } else {
    __shared__ float smf[256];
    float s = 0.f;
    for (int i = t; i < M_EDGES * B_SZ; i += 256) s += essum[i];
    smf[t] = s;
    __syncthreads();
    for (int o = 128; o > 0; o >>= 1) {
      if (t < o) smf[t] += smf[t + o];
      __syncthreads();
    }
    const float S = smf[0];
    __syncthreads();
    float l = 0.f;
    for (int i = t; i < 2016; i += 256) l += lossbuf2[i];
    smf[t] = l;
    __syncthreads();
    for (int o = 128; o > 0; o >>= 1) {
      if (t < o) smf[t] += smf[t + o];
      __syncthreads();
    }
    if (t == 0) {
      const float mean = S * (-255.0f) / 33554432.0f;  // sum(x_i-x_j)=-255*S
      outs[0] = fabsf(mean) + smf[0] * (1.0f / 4225.0f);
    }
  }
}

// Phase D: per node, packed edge list; alpha in LDS; coalesced header.
__global__ __launch_bounds__(256) void k_pD(
    const int* __restrict__ plen, const int* __restrict__ pdat,
    const float* __restrict__ s1_t, const float* __restrict__ s2,
    const float2* __restrict__ pnb, const float* __restrict__ out_e_t,
    float* __restrict__ out) {
  __shared__ int lme[64];
  __shared__ float lcnt[64];
  __shared__ float al[64][32];
  const int n = blockIdx.x;
  const int t = threadIdx.x;
  const int pl = plen[n];
  const int len = pl & 127;
  const float Dn = (float)(pl >> 7);
  const int c = t & 63, bq = t >> 6;
  const size_t nb = (size_t)n * 64 + c;
  const size_t st = (size_t)N_NODES * 64;
  if (len == 0) {
#pragma unroll
    for (int j = 0; j < 8; ++j) out[(bq * 8 + j) * st + nb] = 0.f;
    return;
  }
  if (t < len) {
    const int pe = pdat[n * 64 + t];
    lme[t] = pe & 63;
    lcnt[t] = (float)(pe >> 8);
  }
  __syncthreads();
  {
    const int b = t & 31, lq = t >> 5;
    const float s1v = s1_t[n * 32 + b];
    const float2 pv = pnb[n * 32 + b];
    for (int base = 0; base < len; base += 8) {
      const int li = base + lq;
      if (li < len) {
        const int m = lme[li];
        float sc = s1v + s2[m * 32 + b];
        sc = sc > 0.f ? sc : NEG_SLOPE * sc;
        al[li][b] = lcnt[li] * __expf(sc - pv.x) * pv.y;
      }
    }
  }
  __syncthreads();
  float4 a0 = {0.f, 0.f, 0.f, 0.f}, a1 = {0.f, 0.f, 0.f, 0.f};
  for (int li = 0; li < len; ++li) {
    const int m = lme[li];
    const float4 v0 = *(const float4*)&out_e_t[(m * 64 + c) * 32 + bq * 8];
    const float4 v1 = *(const float4*)&out_e_t[(m * 64 + c) * 32 + bq * 8 + 4];
    const float* alr = al[li];
    a0.x = fmaf(alr[bq * 8 + 0], v0.x, a0.x);
    a0.y = fmaf(alr[bq * 8 + 1], v0.y, a0.y);
    a0.z = fmaf(alr[bq * 8 + 2], v0.z, a0.z);
    a0.w = fmaf(alr[bq * 8 + 3], v0.w, a0.w);
    a1.x = fmaf(alr[bq * 8 + 4], v1.x, a1.x);
    a1.y = fmaf(alr[bq * 8 + 5], v1.y, a1.y);
    a1.z = fmaf(alr[bq * 8 + 6], v1.z, a1.z);
    a1.w = fmaf(alr[bq * 8 + 7], v1.w, a1.w);
  }
  out[(bq * 8 + 0) * st + nb] = Dn * a0.x;
  out[(bq * 8 + 1) * st + nb] = Dn * a0.y;
  out[(bq * 8 + 2) * st + nb] = Dn * a0.z;
  out[(bq * 8 + 3) * st + nb] = Dn * a0.w;
  out[(bq * 8 + 4) * st + nb] = Dn * a1.x;
  out[(bq * 8 + 5) * st + nb] = Dn * a1.y;
  out[(bq * 8 + 6) * st + nb] = Dn * a1.z;
  out[(bq * 8 + 7) * st + nb] = Dn * a1.w;
}

extern "C" void kernel_launch(void* const* d_in, const int* in_sizes, int n_in,
                              void* d_out, int out_size, void* d_ws,
                              size_t ws_size, hipStream_t stream) {
  (void)in_sizes; (void)n_in; (void)out_size; (void)ws_size;
  const float* x = (const float*)d_in[0];
  const float* weight = (const float*)d_in[1];
  const float* att = (const float*)d_in[2];
  const int* node_ids = (const int*)d_in[3];
  float* out = (float*)d_out;

  char* wsb = (char*)d_ws;
  float* es_t = (float*)(wsb);                     // 512KB [m,c,b]
  float* out_e_t = (float*)(wsb + (512 << 10));    // 512KB [m,c,b]
  float* s1_t = (float*)(wsb + (1024 << 10));      // 512KB [n,b]
  int* cntv = (int*)(wsb + (1536 << 10));          // 1MB   [m,n]
  float2* pnb = (float2*)(wsb + (2560 << 10));     // 1MB   [n,b] {mx,invS}
  int* pdat = (int*)(wsb + (3584 << 10));          // 1MB   [n,64] packed m|cnt
  float* s2 = (float*)(wsb + (4608 << 10));        // 8KB
  float* nrm2 = (float*)(wsb + (4616 << 10));      // 8KB
  float* essum = (float*)(wsb + (4624 << 10));     // 8KB
  float* lossbuf2 = (float*)(wsb + (4632 << 10));  // 8KB (2016 floats)
  int* plen = (int*)(wsb + (4640 << 10));          // 16KB [n] len|Dsum<<7

  k_pA<<<1088, 256, 0, stream>>>(x, weight, att, node_ids, s1_t, es_t, s2,
                                 nrm2, essum, cntv);
  k_pB<<<1016, 256, 0, stream>>>(es_t, nrm2, cntv, s1_t, s2, lossbuf2, pnb,
                                 pdat, plen);
  k_pC<<<513, 256, 0, stream>>>(x, node_ids, weight, s1_t, s2, pnb, essum,
                                lossbuf2, out_e_t,
                                out + (size_t)B_SZ * N_NODES * C_DIM);
  k_pD<<<4096, 256, 0, stream>>>(plen, pdat, s1_t, s2, pnb, out_e_t, out);
}